// Round 2
// baseline (511.948 us; speedup 1.0000x reference)
//
#include <hip/hip_runtime.h>
#include <hip/hip_fp16.h>

#define T_STEPS 2048
#define BATCH   256
#define DIN     32
#define HID     8
constexpr int NROWS = BATCH * T_STEPS;  // 524288 (b*T+t) rows

// ---------- fast math helpers ----------
__device__ __forceinline__ float fexp2(float x) {
#if __has_builtin(__builtin_amdgcn_exp2f)
  return __builtin_amdgcn_exp2f(x);
#else
  return exp2f(x);
#endif
}
__device__ __forceinline__ float frcp(float x) {
#if __has_builtin(__builtin_amdgcn_rcpf)
  return __builtin_amdgcn_rcpf(x);
#else
  return 1.0f / x;
#endif
}
__device__ __forceinline__ float fast_sig(float x) {
  float e = fexp2(-1.442695040888963f * x);
  return frcp(1.0f + e);
}
__device__ __forceinline__ float fast_tanh(float x) {
  float e = fexp2(-2.885390081777927f * x);
  return fmaf(2.0f, frcp(1.0f + e), -1.0f);
}

// DPP cross-lane move
template<int CTRL>
__device__ __forceinline__ float dppf(float x) {
  int i = __float_as_int(x);
  int r = __builtin_amdgcn_update_dpp(i, i, CTRL, 0xF, 0xF, false);
  return __int_as_float(r);
}
#define DPP_XOR1 0xB1   // quad_perm {1,0,3,2}
#define DPP_XOR2 0x4E   // quad_perm {2,3,0,1}
#define DPP_MIR8 0x141  // row_half_mirror = xor7 within 8 lanes

struct half4 { __half2 lo, hi; };  // 8 bytes

// ---------- Phase 1: ZX[b][t][unit][gate] = x@Wx + b  (fp16) ----------
// lane j (0..31) owns Wx column j in registers; 2 rows per wave per iter.
__global__ __launch_bounds__(256) void zx_kernel(const float* __restrict__ x,
                                                 const float* __restrict__ Wx,
                                                 const float* __restrict__ bias,
                                                 __half* __restrict__ zx) {
  int tid  = blockIdx.x * 256 + (int)threadIdx.x;
  int wave = tid >> 6;               // 0..2047 (512 blocks x 4 waves)
  int lane = (int)threadIdx.x & 63;
  int j    = lane & 31;              // output column (= gate*8 + unit)
  int r    = lane >> 5;              // which of the 2 rows this half-wave does

  float wxc[32];
#pragma unroll
  for (int d = 0; d < 32; ++d) wxc[d] = Wx[d * 32 + j];
  float bj = bias[j];

  int st = ((j & 7) << 2) + (j >> 3);  // permuted store offset: unit*4 + gate
  int base = wave * 256;               // 256 rows per wave

  for (int it = 0; it < 128; ++it) {
    int row = base + (it << 1) + r;
    const float4* xr = (const float4*)(x + (size_t)row * 32);
    float xv[32];
#pragma unroll
    for (int q = 0; q < 8; ++q) {
      float4 v = xr[q];
      xv[4*q+0] = v.x; xv[4*q+1] = v.y; xv[4*q+2] = v.z; xv[4*q+3] = v.w;
    }
    float a = bj, b2 = 0.0f;
#pragma unroll
    for (int d = 0; d < 32; d += 2) {
      a  = fmaf(xv[d],   wxc[d],   a);
      b2 = fmaf(xv[d+1], wxc[d+1], b2);
    }
    zx[(size_t)row * 32 + st] = __float2half(a + b2);
  }
}

// ---------- Phase 2: the recurrence ----------
// 8 lanes per batch; lane owns hidden unit s, computes all 4 gates.
__global__ __launch_bounds__(64) void lstm_kernel(const __half* __restrict__ zx,
                                                  const float* __restrict__ h0,
                                                  const float* __restrict__ c0,
                                                  const float* __restrict__ Wh,
                                                  float* __restrict__ out) {
  int lane = (int)threadIdx.x;          // 0..63
  int b = blockIdx.x * 8 + (lane >> 3); // batch
  int s = lane & 7;                     // hidden unit

  // gather-register m holds h[s ^ XM[m]] after the DPP sequence
  constexpr int XM[8] = {0, 1, 2, 3, 7, 6, 5, 4};
  float wcf[8][4];
#pragma unroll
  for (int m = 0; m < 8; ++m) {
    int rowj = s ^ XM[m];
#pragma unroll
    for (int g = 0; g < 4; ++g) wcf[m][g] = Wh[rowj * 32 + g * 8 + s];
  }

  float h = h0[b * 8 + s];
  float c = c0[b * 8 + s];

  // row (b,t) = 64 bytes = 8 half4; unit s is half4 index s within row
  const half4* zp = (const half4*)zx + ((size_t)b * T_STEPS) * 8 + s;
  float* op = out + (size_t)b * T_STEPS * 8 + s;

  constexpr int PD = 8;  // prefetch depth (register ring, statically indexed)
  half4 buf[PD];
#pragma unroll
  for (int p = 0; p < PD; ++p) buf[p] = zp[(size_t)p * 8];

  for (int tb = 0; tb < T_STEPS; tb += PD) {
#pragma unroll
    for (int p = 0; p < PD; ++p) {
      float2 zif = __half22float2(buf[p].lo);  // gates i, f
      float2 zgo = __half22float2(buf[p].hi);  // gates g, o
      int tn = tb + PD + p;
      if (tn < T_STEPS) buf[p] = zp[(size_t)tn * 8];

      // allgather h[0..7] within the 8-lane group (3 DPP rounds, 7 moves)
      float rr[8];
      rr[0] = h;
      rr[1] = dppf<DPP_XOR1>(rr[0]);  // h[s^1]
      rr[2] = dppf<DPP_XOR2>(rr[0]);  // h[s^2]
      rr[3] = dppf<DPP_XOR2>(rr[1]);  // h[s^3]
      rr[4] = dppf<DPP_MIR8>(rr[0]);  // h[s^7]
      rr[5] = dppf<DPP_MIR8>(rr[1]);  // h[s^6]
      rr[6] = dppf<DPP_MIR8>(rr[2]);  // h[s^5]
      rr[7] = dppf<DPP_MIR8>(rr[3]);  // h[s^4]

      float za[4] = {zif.x, zif.y, zgo.x, zgo.y};
      float aA[4], aB[4];
#pragma unroll
      for (int g = 0; g < 4; ++g) {
        aA[g] = fmaf(rr[0], wcf[0][g], za[g]);
        aB[g] = rr[4] * wcf[4][g];
      }
#pragma unroll
      for (int m = 1; m < 4; ++m) {
#pragma unroll
        for (int g = 0; g < 4; ++g) {
          aA[g] = fmaf(rr[m],     wcf[m][g],     aA[g]);
          aB[g] = fmaf(rr[m + 4], wcf[m + 4][g], aB[g]);
        }
      }
      float iv = fast_sig (aA[0] + aB[0]);
      float fv = fast_sig (aA[1] + aB[1]);
      float gv = fast_tanh(aA[2] + aB[2]);
      float ov = fast_sig (aA[3] + aB[3]);

      c = fmaf(fv, c, iv * gv);
      h = ov * fast_tanh(c);

      op[(size_t)(tb + p) * 8] = h;
    }
  }
  // final states, appended after outputs
  out[(size_t)BATCH * T_STEPS * 8 +              b * 8 + s] = h;
  out[(size_t)BATCH * T_STEPS * 8 + BATCH * 8 +  b * 8 + s] = c;
}

extern "C" void kernel_launch(void* const* d_in, const int* in_sizes, int n_in,
                              void* d_out, int out_size, void* d_ws, size_t ws_size,
                              hipStream_t stream) {
  const float* x    = (const float*)d_in[0];
  const float* h0   = (const float*)d_in[1];
  const float* c0   = (const float*)d_in[2];
  const float* Wx   = (const float*)d_in[3];
  const float* Wh   = (const float*)d_in[4];
  const float* bias = (const float*)d_in[5];
  float* out = (float*)d_out;
  __half* zx = (__half*)d_ws;  // 256*2048*32*2 = 32 MB scratch

  zx_kernel<<<NROWS / 1024, 256, 0, stream>>>(x, Wx, bias, zx);
  lstm_kernel<<<BATCH / 8, 64, 0, stream>>>(zx, h0, c0, Wh, out);
}